// Round 4
// baseline (1934.775 us; speedup 1.0000x reference)
//
#include <hip/hip_runtime.h>
#include <hip/hip_bf16.h>
#include <stdint.h>

// ---------------------------------------------------------------------------
// Transformer: 6 layers. fp32 residual stream + BN stats; bf16 MFMA GEMMs.
// R4: GEMM gets (a) double-buffered prefetch pipeline (stage t+1 before
// compute t, one vmcnt(0)+barrier per K-step), (b) T2 XOR-swizzled LDS via
// pre-swizzled global source, (c) fused BN-stats epilogue (per-col sum/sumsq
// -> LDS reduce -> global atomicAdd), removing 3 stats passes per layer.
// ---------------------------------------------------------------------------

typedef __bf16 bf16x8 __attribute__((ext_vector_type(8)));
typedef __bf16 bf16x4 __attribute__((ext_vector_type(4)));
typedef float  f32x4  __attribute__((ext_vector_type(4)));

#define DIM_  768
#define SCALE_ 0.125f

__device__ __forceinline__ void gload16(const void* g, void* l) {
  __builtin_amdgcn_global_load_lds(
      (__attribute__((address_space(1))) void*)(g),
      (__attribute__((address_space(3))) void*)(l), 16, 0, 0);
}

// ------------------------- weight transpose + cvt --------------------------
__global__ void transpose_cvt(const float* __restrict__ W, __bf16* __restrict__ WT,
                              int K, int N) {
  __shared__ float t[32][33];
  const size_t zoff = (size_t)blockIdx.z * K * N;
  W  += zoff; WT += zoff;
  const int bx = blockIdx.x * 32;
  const int by = blockIdx.y * 32;
  for (int j = threadIdx.y; j < 32; j += 8)
    t[j][threadIdx.x] = W[(size_t)(by + j) * N + bx + threadIdx.x];
  __syncthreads();
  for (int j = threadIdx.y; j < 32; j += 8)
    WT[(size_t)(bx + j) * K + by + threadIdx.x] = (__bf16)t[threadIdx.x][j];
}

// ------------------------------- copies ------------------------------------
__global__ void copy_f32(const float* __restrict__ src, float* __restrict__ dst) {
  const int i = blockIdx.x * 256 + threadIdx.x;
  *(f32x4*)(dst + (size_t)i * 4) = *(const f32x4*)(src + (size_t)i * 4);
}

// ------------------------------ BN stats (layer-0 bn1 only) ----------------
__global__ void bn_stats_part(const float* __restrict__ x, float* __restrict__ part) {
  const int col = blockIdx.x * 256 + threadIdx.x;
  const int r0  = blockIdx.y * 64;
  const float* p = x + (size_t)r0 * DIM_ + col;
  float s = 0.f, s2 = 0.f;
  for (int r = 0; r < 64; ++r) {
    float v = p[(size_t)r * DIM_];
    s += v; s2 += v * v;
  }
  float* q = part + ((size_t)blockIdx.y * DIM_ + col) * 2;
  q[0] = s; q[1] = s2;
}

__global__ void bn_stats_fin(const float* __restrict__ part, const float* __restrict__ g,
                             const float* __restrict__ b, float* __restrict__ sc) {
  const int col = blockIdx.x * 256 + threadIdx.x;
  float s = 0.f, s2 = 0.f;
  for (int p = 0; p < 196; ++p) {
    s  += part[((size_t)p * DIM_ + col) * 2];
    s2 += part[((size_t)p * DIM_ + col) * 2 + 1];
  }
  const float mean = s * (1.f / 12544.f);
  const float var  = s2 * (1.f / 12544.f) - mean * mean;
  const float rstd = rsqrtf(var + 1e-5f);
  const float scale = rstd * g[col];
  sc[col]        = scale;
  sc[DIM_ + col] = b[col] - mean * scale;
}

// finalize from atomically-accumulated [col][2] sums
__global__ void bn_fin2(const float* __restrict__ acc, const float* __restrict__ g,
                        const float* __restrict__ b, float* __restrict__ sc) {
  const int col = blockIdx.x * 256 + threadIdx.x;
  const float s  = acc[col * 2];
  const float s2 = acc[col * 2 + 1];
  const float mean = s * (1.f / 12544.f);
  const float var  = s2 * (1.f / 12544.f) - mean * mean;
  const float rstd = rsqrtf(var + 1e-5f);
  const float scale = rstd * g[col];
  sc[col]        = scale;
  sc[DIM_ + col] = b[col] - mean * scale;
}

// ------------------------------ BN apply -----------------------------------
__global__ void bn_apply_f32(const float* __restrict__ x, const float* __restrict__ sc,
                             __bf16* __restrict__ h) {
  const int i = blockIdx.x * 256 + threadIdx.x;
  const int c4 = i % 192;
  f32x4 v  = *(const f32x4*)(x + (size_t)i * 4);
  f32x4 scl = *(const f32x4*)(sc + c4 * 4);
  f32x4 sh  = *(const f32x4*)(sc + DIM_ + c4 * 4);
  f32x4 y = v * scl + sh;
  bf16x4 o;
  o[0] = (__bf16)y[0]; o[1] = (__bf16)y[1]; o[2] = (__bf16)y[2]; o[3] = (__bf16)y[3];
  *(bf16x4*)(h + (size_t)i * 4) = o;
}

__global__ void bn_gelu_apply(const __bf16* __restrict__ f1, const float* __restrict__ sc,
                              __bf16* __restrict__ h) {
  const int i = blockIdx.x * 256 + threadIdx.x;
  const int c4 = i % 192;
  bf16x4 v4 = *(const bf16x4*)(f1 + (size_t)i * 4);
  f32x4 scl = *(const f32x4*)(sc + c4 * 4);
  f32x4 sh  = *(const f32x4*)(sc + DIM_ + c4 * 4);
  bf16x4 o;
#pragma unroll
  for (int j = 0; j < 4; ++j) {
    float y = (float)v4[j] * scl[j] + sh[j];
    float gl = 0.5f * y * (1.f + erff(y * 0.70710678118654752f));
    o[j] = (__bf16)gl;
  }
  *(bf16x4*)(h + (size_t)i * 4) = o;
}

// -------------------------------- GEMM -------------------------------------
// C[M x N] = A[M x K] @ BT[N x K]^T ; 128x128 tile, BK=64, 256 thr (4 waves).
// Double-buffered prefetch: stage tile t+1 before computing tile t.
// LDS tiles XOR-swizzled (chunk ^ (row&7)) via pre-swizzled global source.
// EPI 0: outB = bf16(acc + bias[col]); EPI 1: outF += acc + bias[col];
// EPI 2: outB = bf16(acc + bias[row]).
// STATS: accumulate per-column sum/sumsq of the final value into statsAcc.
template <int EPI, int STATS>
__global__ __launch_bounds__(256, 2) void gemm128(
    const __bf16* __restrict__ A, int lda,
    const __bf16* __restrict__ BT, int K,
    const float* __restrict__ bias,
    __bf16* __restrict__ outB, float* outF, int ldc,
    float* __restrict__ statsAcc) {
  __shared__ __bf16 sA[2][128 * 64];
  __shared__ __bf16 sB[2][128 * 64];
  __shared__ float scol[256];
  const int tid = threadIdx.x;
  const int lane = tid & 63, wv = tid >> 6;
  const int l15 = lane & 15, hi = lane >> 4;
  const int m0 = blockIdx.x * 128, n0 = blockIdx.y * 128;
  const __bf16* Ab = A + (size_t)m0 * lda;
  const __bf16* Bb = BT + (size_t)n0 * K;
  const int wr = (wv >> 1) * 64, wc = (wv & 1) * 64;

  f32x4 acc[4][4] = {};

#define STAGE(kt, buf)                                                        \
  {                                                                           \
    const int k0_ = (kt) << 6;                                                \
    _Pragma("unroll")                                                         \
    for (int i_ = 0; i_ < 4; ++i_) {                                          \
      const int o_ = i_ * 4096 + tid * 16;                                    \
      const int row_ = o_ >> 7;                                               \
      const int j_ = (o_ >> 4) & 7;                                           \
      const int src_ = (j_ ^ (row_ & 7)) << 3;                                \
      gload16(Ab + (size_t)row_ * lda + k0_ + src_,                           \
              &sA[buf][i_ * 2048 + wv * 512]);                                \
      gload16(Bb + (size_t)row_ * K + k0_ + src_,                             \
              &sB[buf][i_ * 2048 + wv * 512]);                                \
    }                                                                         \
  }

  if (STATS && tid < 256) scol[tid] = 0.f;

  STAGE(0, 0);
  asm volatile("s_waitcnt vmcnt(0)" ::: "memory");
  __syncthreads();

  const int nkt = K >> 6;
  int cur = 0;
  for (int kt = 0; kt < nkt; ++kt) {
    if (kt + 1 < nkt) STAGE(kt + 1, cur ^ 1);
    const char* cA = (const char*)sA[cur];
    const char* cB = (const char*)sB[cur];
#pragma unroll
    for (int ks = 0; ks < 2; ++ks) {
      bf16x8 af[4], bfr[4];
#pragma unroll
      for (int m = 0; m < 4; ++m) {
        const int row = wr + m * 16 + l15;
        af[m] = *(const bf16x8*)(cA + row * 128 +
                                 ((ks * 64 + hi * 16) ^ ((row & 7) << 4)));
      }
#pragma unroll
      for (int n = 0; n < 4; ++n) {
        const int row = wc + n * 16 + l15;
        bfr[n] = *(const bf16x8*)(cB + row * 128 +
                                  ((ks * 64 + hi * 16) ^ ((row & 7) << 4)));
      }
#pragma unroll
      for (int m = 0; m < 4; ++m)
#pragma unroll
        for (int n = 0; n < 4; ++n)
          acc[m][n] = __builtin_amdgcn_mfma_f32_16x16x32_bf16(af[m], bfr[n], acc[m][n], 0, 0, 0);
    }
    asm volatile("s_waitcnt vmcnt(0)" ::: "memory");
    __syncthreads();
    cur ^= 1;
  }
#undef STAGE

  float cs[4], cs2[4];
  if (STATS)
#pragma unroll
    for (int n = 0; n < 4; ++n) { cs[n] = 0.f; cs2[n] = 0.f; }

#pragma unroll
  for (int m = 0; m < 4; ++m)
#pragma unroll
    for (int n = 0; n < 4; ++n) {
      const int cc = n0 + wc + n * 16 + l15;
      const float bc = (EPI == 2) ? 0.f : bias[cc];
#pragma unroll
      for (int r = 0; r < 4; ++r) {
        const int rr = m0 + wr + m * 16 + hi * 4 + r;
        const float val = acc[m][n][r] + ((EPI == 2) ? bias[rr] : bc);
        float fv;
        if (EPI == 1) {
          float* p = outF + (size_t)rr * ldc + cc;
          fv = *p + val;
          *p = fv;
        } else {
          fv = val;
          outB[(size_t)rr * ldc + cc] = (__bf16)fv;
        }
        if (STATS) { cs[n] += fv; cs2[n] += fv * fv; }
      }
    }

  if (STATS) {
#pragma unroll
    for (int n = 0; n < 4; ++n) {
      float s = cs[n], s2 = cs2[n];
      s += __shfl_xor(s, 16); s2 += __shfl_xor(s2, 16);
      s += __shfl_xor(s, 32); s2 += __shfl_xor(s2, 32);
      if (lane < 16) {
        atomicAdd(&scol[(wc + n * 16 + l15) * 2], s);
        atomicAdd(&scol[(wc + n * 16 + l15) * 2 + 1], s2);
      }
    }
    __syncthreads();
    if (tid < 128) {
      atomicAdd(&statsAcc[(size_t)(n0 + tid) * 2], scol[tid * 2]);
      atomicAdd(&statsAcc[(size_t)(n0 + tid) * 2 + 1], scol[tid * 2 + 1]);
    }
  }
}

// ------------------------------ attention ----------------------------------
#define SV_OFF 26624
#define SP_OFF 83968
__global__ __launch_bounds__(512, 1) void attn_kernel(
    const __bf16* __restrict__ qk, const __bf16* __restrict__ vT,
    __bf16* __restrict__ og) {
  __shared__ __align__(16) char smem[149504];
  const int bh = blockIdx.x, bb = bh >> 3, hh = bh & 7;
  const int tid = threadIdx.x, lane = tid & 63, wv = tid >> 6;
  const int l15 = lane & 15, hi = lane >> 4;

  const __bf16* qbase = qk + (size_t)bb * (196 * 1024) + hh * 64;
  const __bf16* kbase = qbase + 512;
  const __bf16* vbase = vT + (size_t)(hh * 112) * 12544 + bb * 196;
  __bf16* obase = og + (size_t)bb * (196 * 896) + hh * 112;

  char* sV = smem + SV_OFF;
  char* sP = smem + SP_OFF + wv * 8192;

  for (int s = tid; s < 1664; s += 512) {
    const int n = s >> 3, j = s & 7;
    const int row = (n < 196) ? n : 195;
    const int k8 = j ^ (n & 7);
    gload16(kbase + (size_t)row * 1024 + k8 * 8, smem + ((s >> 6) << 10));
  }
  for (int c = tid; c < 112 * 49; c += 512) {
    const int d = c / 49, c8 = c - d * 49;
    const bf16x4 v4 = *(const bf16x4*)(vbase + (size_t)d * 12544 + c8 * 4);
    *(bf16x4*)(sV + d * 512 + ((c8 * 8) ^ ((d & 7) << 4))) = v4;
  }
  {
    bf16x4 z = {};
    for (int c = tid; c < 112 * 7; c += 512) {
      const int d = c / 7, c8 = 49 + (c - d * 7);
      *(bf16x4*)(sV + d * 512 + ((c8 * 8) ^ ((d & 7) << 4))) = z;
    }
  }
  asm volatile("s_waitcnt vmcnt(0)" ::: "memory");
  __syncthreads();

  const int xm = (l15 & 7) << 4;
  for (int qt = wv; qt < 13; qt += 8) {
    const int q0 = qt * 16;
    int qn = q0 + l15; if (qn > 195) qn = 195;
    const __bf16* qp = qbase + (size_t)qn * 1024 + hi * 8;
    const bf16x8 qa0 = *(const bf16x8*)(qp);
    const bf16x8 qa1 = *(const bf16x8*)(qp + 32);

    f32x4 s[13] = {};
#pragma unroll
    for (int nf = 0; nf < 13; ++nf) {
      const int j = nf * 16 + l15;
      const bf16x8 kb0 = *(const bf16x8*)(smem + j * 128 + ((hi * 16) ^ xm));
      const bf16x8 kb1 = *(const bf16x8*)(smem + j * 128 + ((64 + hi * 16) ^ xm));
      s[nf] = __builtin_amdgcn_mfma_f32_16x16x32_bf16(qa0, kb0, s[nf], 0, 0, 0);
      s[nf] = __builtin_amdgcn_mfma_f32_16x16x32_bf16(qa1, kb1, s[nf], 0, 0, 0);
    }

#pragma unroll
    for (int r = 0; r < 4; ++r) {
      float mx = -3.0e38f;
#pragma unroll
      for (int nf = 0; nf < 12; ++nf) mx = fmaxf(mx, s[nf][r]);
      if (l15 < 4) mx = fmaxf(mx, s[12][r]);
#pragma unroll
      for (int off = 1; off < 16; off <<= 1) mx = fmaxf(mx, __shfl_xor(mx, off));
      float sum = 0.f;
#pragma unroll
      for (int nf = 0; nf < 13; ++nf) {
        const bool valid = (nf < 12) || (l15 < 4);
        const float p = valid ? __expf((s[nf][r] - mx) * SCALE_) : 0.f;
        s[nf][r] = p; sum += p;
      }
#pragma unroll
      for (int off = 1; off < 16; off <<= 1) sum += __shfl_xor(sum, off);
      const float inv = 1.f / sum;
#pragma unroll
      for (int nf = 0; nf < 13; ++nf) s[nf][r] *= inv;
    }

#pragma unroll
    for (int r = 0; r < 4; ++r) {
      const int row = hi * 4 + r;
      const int rm = (row & 7) << 4;
      char* rp = sP + row * 512;
#pragma unroll
      for (int nf = 0; nf < 13; ++nf)
        *(__bf16*)(rp + (((nf * 16 + l15) * 2) ^ rm)) = (__bf16)s[nf][r];
      *(__bf16*)(rp + (((208 + l15) * 2) ^ rm)) = (__bf16)0.f;
    }

    f32x4 oa[7] = {};
#pragma unroll
    for (int kk = 0; kk < 7; ++kk) {
      const bf16x8 pa = *(const bf16x8*)(sP + l15 * 512 + ((kk * 64 + hi * 16) ^ xm));
#pragma unroll
      for (int nf = 0; nf < 7; ++nf) {
        const int d = nf * 16 + l15;
        const bf16x8 vbf = *(const bf16x8*)(sV + d * 512 + ((kk * 64 + hi * 16) ^ xm));
        oa[nf] = __builtin_amdgcn_mfma_f32_16x16x32_bf16(pa, vbf, oa[nf], 0, 0, 0);
      }
    }
#pragma unroll
    for (int nf = 0; nf < 7; ++nf)
#pragma unroll
      for (int r = 0; r < 4; ++r) {
        const int q = q0 + hi * 4 + r;
        if (q < 196) obase[(size_t)q * 896 + nf * 16 + l15] = (__bf16)oa[nf][r];
      }
  }
}

// ------------------------------- launch ------------------------------------
extern "C" void kernel_launch(void* const* d_in, const int* in_sizes, int n_in,
                              void* d_out, int out_size, void* d_ws, size_t ws_size,
                              hipStream_t stream) {
  (void)in_sizes; (void)n_in; (void)out_size; (void)ws_size;
  const float* x_in  = (const float*)d_in[0];
  const float* bn1_g = (const float*)d_in[1];
  const float* bn1_b = (const float*)d_in[2];
  const float* Wqk   = (const float*)d_in[3];
  const float* bqk   = (const float*)d_in[4];
  const float* Wv    = (const float*)d_in[5];
  const float* bv    = (const float*)d_in[6];
  const float* Wo    = (const float*)d_in[7];
  const float* bo    = (const float*)d_in[8];
  const float* bn2_g = (const float*)d_in[9];
  const float* bn2_b = (const float*)d_in[10];
  const float* W1    = (const float*)d_in[11];
  const float* b1    = (const float*)d_in[12];
  const float* bn3_g = (const float*)d_in[13];
  const float* bn3_b = (const float*)d_in[14];
  const float* W2    = (const float*)d_in[15];
  const float* b2    = (const float*)d_in[16];

  char* ws = (char*)d_ws;
  float*  xb   = (float*)(ws + 0);            // 12544x768 f32
  __bf16* wqkT = (__bf16*)(ws + 38535168);    // 6 x 1024 x 384
  __bf16* wvT  = (__bf16*)(ws + 43253760);    // 6 x 896 x 768
  __bf16* woT  = (__bf16*)(ws + 51511296);    // 6 x 768 x 896
  __bf16* w1T  = (__bf16*)(ws + 59768832);    // 6 x 768 x 768
  __bf16* w2T  = (__bf16*)(ws + 66846720);    // 6 x 768 x 768
  __bf16* hb   = (__bf16*)(ws + 73924608);    // 12544x768 bf16
  __bf16* qkb  = (__bf16*)(ws + 93192192);    // 12544x1024 bf16 (also f1 reuse)
  __bf16* vTb  = (__bf16*)(ws + 118882304);   // 896x12544 bf16 (V^T)
  __bf16* obuf = (__bf16*)(ws + 141361152);   // 12544x896 bf16
  float*  part = (float*)(ws + 163840000);    // 196x768x2 f32
  float*  sc   = (float*)(ws + 165044224);    // 2x768 f32
  float*  sAcc = (float*)(ws + 165051392);    // 768x2 f32 stats accumulator
  __bf16* f1b  = qkb;

  const dim3 tb(256);

  transpose_cvt<<<dim3(32, 12, 6), dim3(32, 8), 0, stream>>>(Wqk, wqkT, 384, 1024);
  transpose_cvt<<<dim3(28, 24, 6), dim3(32, 8), 0, stream>>>(Wv,  wvT,  768, 896);
  transpose_cvt<<<dim3(24, 28, 6), dim3(32, 8), 0, stream>>>(Wo,  woT,  896, 768);
  transpose_cvt<<<dim3(24, 24, 6), dim3(32, 8), 0, stream>>>(W1,  w1T,  768, 768);
  transpose_cvt<<<dim3(24, 24, 6), dim3(32, 8), 0, stream>>>(W2,  w2T,  768, 768);
  copy_f32<<<9408, tb, 0, stream>>>(x_in, xb);

  // layer-0 bn1 stats (standalone)
  bn_stats_part<<<dim3(3, 196), tb, 0, stream>>>(xb, part);
  bn_stats_fin<<<3, tb, 0, stream>>>(part, bn1_g, bn1_b, sc);

  for (int i = 0; i < 6; ++i) {
    const __bf16* wqkT_i = wqkT + (size_t)i * 1024 * 384;
    const __bf16* wvT_i  = wvT  + (size_t)i * 896 * 768;
    const __bf16* woT_i  = woT  + (size_t)i * 768 * 896;
    const __bf16* w1T_i  = w1T  + (size_t)i * 768 * 768;
    const __bf16* w2T_i  = w2T  + (size_t)i * 768 * 768;

    // --- attention block ---  (sc currently holds bn1 scale/shift)
    bn_apply_f32<<<9408, tb, 0, stream>>>(xb, sc, hb);
    gemm128<0, 0><<<dim3(98, 8), tb, 0, stream>>>(hb + 384, 768, wqkT_i, 384,
                                                  bqk + i * 1024, qkb, nullptr, 1024, nullptr);
    gemm128<2, 0><<<dim3(7, 98), tb, 0, stream>>>(wvT_i, 768, hb, 768,
                                                  bv + i * 896, vTb, nullptr, 12544, nullptr);
    attn_kernel<<<512, dim3(512), 0, stream>>>(qkb, vTb, obuf);
    hipMemsetAsync(sAcc, 0, 768 * 2 * sizeof(float), stream);
    gemm128<1, 1><<<dim3(98, 6), tb, 0, stream>>>(obuf, 896, woT_i, 896,
                                                  bo + i * 768, nullptr, xb, 768, sAcc);

    // --- feedforward block ---
    bn_fin2<<<3, tb, 0, stream>>>(sAcc, bn2_g + i * 768, bn2_b + i * 768, sc);
    bn_apply_f32<<<9408, tb, 0, stream>>>(xb, sc, hb);
    hipMemsetAsync(sAcc, 0, 768 * 2 * sizeof(float), stream);
    gemm128<0, 1><<<dim3(98, 6), tb, 0, stream>>>(hb, 768, w1T_i, 768,
                                                  b1 + i * 768, f1b, nullptr, 768, sAcc);
    bn_fin2<<<3, tb, 0, stream>>>(sAcc, bn3_g + i * 768, bn3_b + i * 768, sc);
    bn_gelu_apply<<<9408, tb, 0, stream>>>(f1b, sc, hb);
    hipMemsetAsync(sAcc, 0, 768 * 2 * sizeof(float), stream);
    gemm128<1, 1><<<dim3(98, 6), tb, 0, stream>>>(hb, 768, w2T_i, 768,
                                                  b2 + i * 768, nullptr, xb, 768, sAcc);
    if (i < 5)
      bn_fin2<<<3, tb, 0, stream>>>(sAcc, bn1_g + (i + 1) * 768, bn1_b + (i + 1) * 768, sc);
  }
  copy_f32<<<9408, tb, 0, stream>>>(xb, (float*)d_out);
}

// Round 5
// 1875.927 us; speedup vs baseline: 1.0314x; 1.0314x over previous
//
#include <hip/hip_runtime.h>
#include <hip/hip_bf16.h>
#include <stdint.h>

// ---------------------------------------------------------------------------
// Transformer: 6 layers. fp32 residual stream + BN stats; bf16 MFMA GEMMs.
// R5: GEMM uses true T3/T4 pipeline — double-buffered LDS, counted
// s_waitcnt vmcnt(8) + raw s_barrier (prefetch loads stay in flight across
// the compute phase; __syncthreads would force a vmcnt(0) drain).
// T2 XOR-swizzled LDS (pre-swizzled global src, linear gload dest).
// Fused BN-stats epilogues; bn_fin2 self-zeroes the accumulator (no memsets).
// ---------------------------------------------------------------------------

typedef __bf16 bf16x8 __attribute__((ext_vector_type(8)));
typedef __bf16 bf16x4 __attribute__((ext_vector_type(4)));
typedef float  f32x4  __attribute__((ext_vector_type(4)));

#define DIM_  768
#define SCALE_ 0.125f

__device__ __forceinline__ void gload16(const void* g, void* l) {
  __builtin_amdgcn_global_load_lds(
      (__attribute__((address_space(1))) void*)(g),
      (__attribute__((address_space(3))) void*)(l), 16, 0, 0);
}

// ------------------------- weight transpose + cvt --------------------------
__global__ void transpose_cvt(const float* __restrict__ W, __bf16* __restrict__ WT,
                              int K, int N) {
  __shared__ float t[32][33];
  const size_t zoff = (size_t)blockIdx.z * K * N;
  W  += zoff; WT += zoff;
  const int bx = blockIdx.x * 32;
  const int by = blockIdx.y * 32;
  for (int j = threadIdx.y; j < 32; j += 8)
    t[j][threadIdx.x] = W[(size_t)(by + j) * N + bx + threadIdx.x];
  __syncthreads();
  for (int j = threadIdx.y; j < 32; j += 8)
    WT[(size_t)(bx + j) * K + by + threadIdx.x] = (__bf16)t[threadIdx.x][j];
}

// ------------------------------- copies ------------------------------------
__global__ void copy_f32(const float* __restrict__ src, float* __restrict__ dst) {
  const int i = blockIdx.x * 256 + threadIdx.x;
  *(f32x4*)(dst + (size_t)i * 4) = *(const f32x4*)(src + (size_t)i * 4);
}

// ------------------------------ BN stats (layer-0 bn1 only) ----------------
__global__ void bn_stats_part(const float* __restrict__ x, float* __restrict__ part) {
  const int col = blockIdx.x * 256 + threadIdx.x;
  const int r0  = blockIdx.y * 64;
  const float* p = x + (size_t)r0 * DIM_ + col;
  float s = 0.f, s2 = 0.f;
  for (int r = 0; r < 64; ++r) {
    float v = p[(size_t)r * DIM_];
    s += v; s2 += v * v;
  }
  float* q = part + ((size_t)blockIdx.y * DIM_ + col) * 2;
  q[0] = s; q[1] = s2;
}

__global__ void bn_stats_fin(const float* __restrict__ part, const float* __restrict__ g,
                             const float* __restrict__ b, float* __restrict__ sc) {
  const int col = blockIdx.x * 256 + threadIdx.x;
  float s = 0.f, s2 = 0.f;
  for (int p = 0; p < 196; ++p) {
    s  += part[((size_t)p * DIM_ + col) * 2];
    s2 += part[((size_t)p * DIM_ + col) * 2 + 1];
  }
  const float mean = s * (1.f / 12544.f);
  const float var  = s2 * (1.f / 12544.f) - mean * mean;
  const float rstd = rsqrtf(var + 1e-5f);
  const float scale = rstd * g[col];
  sc[col]        = scale;
  sc[DIM_ + col] = b[col] - mean * scale;
}

// finalize from atomically-accumulated [col][2] sums; self-zero for next use
__global__ void bn_fin2(float* __restrict__ acc, const float* __restrict__ g,
                        const float* __restrict__ b, float* __restrict__ sc) {
  const int col = blockIdx.x * 256 + threadIdx.x;
  const float s  = acc[col * 2];
  const float s2 = acc[col * 2 + 1];
  acc[col * 2] = 0.f; acc[col * 2 + 1] = 0.f;
  const float mean = s * (1.f / 12544.f);
  const float var  = s2 * (1.f / 12544.f) - mean * mean;
  const float rstd = rsqrtf(var + 1e-5f);
  const float scale = rstd * g[col];
  sc[col]        = scale;
  sc[DIM_ + col] = b[col] - mean * scale;
}

// ------------------------------ BN apply -----------------------------------
__global__ void bn_apply_f32(const float* __restrict__ x, const float* __restrict__ sc,
                             __bf16* __restrict__ h) {
  const int i = blockIdx.x * 256 + threadIdx.x;
  const int c4 = i % 192;
  f32x4 v  = *(const f32x4*)(x + (size_t)i * 4);
  f32x4 scl = *(const f32x4*)(sc + c4 * 4);
  f32x4 sh  = *(const f32x4*)(sc + DIM_ + c4 * 4);
  f32x4 y = v * scl + sh;
  bf16x4 o;
  o[0] = (__bf16)y[0]; o[1] = (__bf16)y[1]; o[2] = (__bf16)y[2]; o[3] = (__bf16)y[3];
  *(bf16x4*)(h + (size_t)i * 4) = o;
}

__global__ void bn_gelu_apply(const __bf16* __restrict__ f1, const float* __restrict__ sc,
                              __bf16* __restrict__ h) {
  const int i = blockIdx.x * 256 + threadIdx.x;
  const int c4 = i % 192;
  bf16x4 v4 = *(const bf16x4*)(f1 + (size_t)i * 4);
  f32x4 scl = *(const f32x4*)(sc + c4 * 4);
  f32x4 sh  = *(const f32x4*)(sc + DIM_ + c4 * 4);
  bf16x4 o;
#pragma unroll
  for (int j = 0; j < 4; ++j) {
    float y = (float)v4[j] * scl[j] + sh[j];
    float gl = 0.5f * y * (1.f + erff(y * 0.70710678118654752f));
    o[j] = (__bf16)gl;
  }
  *(bf16x4*)(h + (size_t)i * 4) = o;
}

// -------------------------------- GEMM -------------------------------------
// C[M x N] = A[M x K] @ BT[N x K]^T ; 128x128 tile, BK=64, 256 thr (4 waves).
// T3/T4: double-buffer, STAGE(t+1) issued, then s_waitcnt vmcnt(8) (waits
// only tile-t loads) + raw s_barrier; prefetch stays in flight across MFMAs.
// LDS tiles XOR-swizzled (chunk ^ (row&7)) via pre-swizzled global source.
// EPI 0: outB = bf16(acc + bias[col]); EPI 1: outF += acc + bias[col];
// EPI 2: outB = bf16(acc + bias[row]).
// STATS: accumulate per-column sum/sumsq of final values into statsAcc.
template <int EPI, int STATS>
__global__ __launch_bounds__(256, 2) void gemm128(
    const __bf16* __restrict__ A, int lda,
    const __bf16* __restrict__ BT, int K,
    const float* __restrict__ bias,
    __bf16* __restrict__ outB, float* outF, int ldc,
    float* __restrict__ statsAcc) {
  __shared__ __bf16 sA[2][128 * 64];
  __shared__ __bf16 sB[2][128 * 64];
  __shared__ float scol[256];
  const int tid = threadIdx.x;
  const int lane = tid & 63, wv = tid >> 6;
  const int l15 = lane & 15, hi = lane >> 4;
  const int m0 = blockIdx.x * 128, n0 = blockIdx.y * 128;
  const __bf16* Ab = A + (size_t)m0 * lda;
  const __bf16* Bb = BT + (size_t)n0 * K;
  const int wr = (wv >> 1) * 64, wc = (wv & 1) * 64;

  f32x4 acc[4][4] = {};

#define STAGE(kt, buf)                                                        \
  {                                                                           \
    const int k0_ = (kt) << 6;                                                \
    _Pragma("unroll")                                                         \
    for (int i_ = 0; i_ < 4; ++i_) {                                          \
      const int o_ = i_ * 4096 + tid * 16;                                    \
      const int row_ = o_ >> 7;                                               \
      const int j_ = (o_ >> 4) & 7;                                           \
      const int src_ = (j_ ^ (row_ & 7)) << 3;                                \
      gload16(Ab + (size_t)row_ * lda + k0_ + src_,                           \
              &sA[buf][i_ * 2048 + wv * 512]);                                \
      gload16(Bb + (size_t)row_ * K + k0_ + src_,                             \
              &sB[buf][i_ * 2048 + wv * 512]);                                \
    }                                                                         \
  }

  if (STATS) scol[tid] = 0.f;

  STAGE(0, 0);

  const int nkt = K >> 6;
  int cur = 0;
  for (int kt = 0; kt < nkt; ++kt) {
    if (kt + 1 < nkt) {
      STAGE(kt + 1, cur ^ 1);
      asm volatile("s_waitcnt vmcnt(8)" ::: "memory");   // tile-t loads done
    } else {
      asm volatile("s_waitcnt vmcnt(0)" ::: "memory");   // final drain
    }
    __builtin_amdgcn_s_barrier();   // all waves' tile-t loads visible
    const char* cA = (const char*)sA[cur];
    const char* cB = (const char*)sB[cur];
#pragma unroll
    for (int ks = 0; ks < 2; ++ks) {
      bf16x8 af[4], bfr[4];
#pragma unroll
      for (int m = 0; m < 4; ++m) {
        const int row = wr + m * 16 + l15;
        af[m] = *(const bf16x8*)(cA + row * 128 +
                                 ((ks * 64 + hi * 16) ^ ((row & 7) << 4)));
      }
#pragma unroll
      for (int n = 0; n < 4; ++n) {
        const int row = wc + n * 16 + l15;
        bfr[n] = *(const bf16x8*)(cB + row * 128 +
                                  ((ks * 64 + hi * 16) ^ ((row & 7) << 4)));
      }
#pragma unroll
      for (int m = 0; m < 4; ++m)
#pragma unroll
        for (int n = 0; n < 4; ++n)
          acc[m][n] = __builtin_amdgcn_mfma_f32_16x16x32_bf16(af[m], bfr[n], acc[m][n], 0, 0, 0);
    }
    __builtin_amdgcn_s_barrier();   // reads of buf done before next overwrite
    cur ^= 1;
  }
#undef STAGE

  float cs[4], cs2[4];
  if (STATS)
#pragma unroll
    for (int n = 0; n < 4; ++n) { cs[n] = 0.f; cs2[n] = 0.f; }

#pragma unroll
  for (int m = 0; m < 4; ++m)
#pragma unroll
    for (int n = 0; n < 4; ++n) {
      const int cc = n0 + wc + n * 16 + l15;
      const float bc = (EPI == 2) ? 0.f : bias[cc];
#pragma unroll
      for (int r = 0; r < 4; ++r) {
        const int rr = m0 + wr + m * 16 + hi * 4 + r;
        const float val = acc[m][n][r] + ((EPI == 2) ? bias[rr] : bc);
        float fv;
        if (EPI == 1) {
          float* p = outF + (size_t)rr * ldc + cc;
          fv = *p + val;
          *p = fv;
        } else {
          fv = val;
          outB[(size_t)rr * ldc + cc] = (__bf16)fv;
        }
        if (STATS) { cs[n] += fv; cs2[n] += fv * fv; }
      }
    }

  if (STATS) {
#pragma unroll
    for (int n = 0; n < 4; ++n) {
      float s = cs[n], s2 = cs2[n];
      s += __shfl_xor(s, 16); s2 += __shfl_xor(s2, 16);
      s += __shfl_xor(s, 32); s2 += __shfl_xor(s2, 32);
      if (lane < 16) {
        atomicAdd(&scol[(wc + n * 16 + l15) * 2], s);
        atomicAdd(&scol[(wc + n * 16 + l15) * 2 + 1], s2);
      }
    }
    __syncthreads();
    if (tid < 128) {
      atomicAdd(&statsAcc[(size_t)(n0 + tid) * 2], scol[tid * 2]);
      atomicAdd(&statsAcc[(size_t)(n0 + tid) * 2 + 1], scol[tid * 2 + 1]);
    }
  }
}

// ------------------------------ attention ----------------------------------
#define SV_OFF 26624
#define SP_OFF 83968
__global__ __launch_bounds__(512, 1) void attn_kernel(
    const __bf16* __restrict__ qk, const __bf16* __restrict__ vT,
    __bf16* __restrict__ og) {
  __shared__ __align__(16) char smem[149504];
  const int bh = blockIdx.x, bb = bh >> 3, hh = bh & 7;
  const int tid = threadIdx.x, lane = tid & 63, wv = tid >> 6;
  const int l15 = lane & 15, hi = lane >> 4;

  const __bf16* qbase = qk + (size_t)bb * (196 * 1024) + hh * 64;
  const __bf16* kbase = qbase + 512;
  const __bf16* vbase = vT + (size_t)(hh * 112) * 12544 + bb * 196;
  __bf16* obase = og + (size_t)bb * (196 * 896) + hh * 112;

  char* sV = smem + SV_OFF;
  char* sP = smem + SP_OFF + wv * 8192;

  for (int s = tid; s < 1664; s += 512) {
    const int n = s >> 3, j = s & 7;
    const int row = (n < 196) ? n : 195;
    const int k8 = j ^ (n & 7);
    gload16(kbase + (size_t)row * 1024 + k8 * 8, smem + ((s >> 6) << 10));
  }
  for (int c = tid; c < 112 * 49; c += 512) {
    const int d = c / 49, c8 = c - d * 49;
    const bf16x4 v4 = *(const bf16x4*)(vbase + (size_t)d * 12544 + c8 * 4);
    *(bf16x4*)(sV + d * 512 + ((c8 * 8) ^ ((d & 7) << 4))) = v4;
  }
  {
    bf16x4 z = {};
    for (int c = tid; c < 112 * 7; c += 512) {
      const int d = c / 7, c8 = 49 + (c - d * 7);
      *(bf16x4*)(sV + d * 512 + ((c8 * 8) ^ ((d & 7) << 4))) = z;
    }
  }
  asm volatile("s_waitcnt vmcnt(0)" ::: "memory");
  __syncthreads();

  const int xm = (l15 & 7) << 4;
  for (int qt = wv; qt < 13; qt += 8) {
    const int q0 = qt * 16;
    int qn = q0 + l15; if (qn > 195) qn = 195;
    const __bf16* qp = qbase + (size_t)qn * 1024 + hi * 8;
    const bf16x8 qa0 = *(const bf16x8*)(qp);
    const bf16x8 qa1 = *(const bf16x8*)(qp + 32);

    f32x4 s[13] = {};
#pragma unroll
    for (int nf = 0; nf < 13; ++nf) {
      const int j = nf * 16 + l15;
      const bf16x8 kb0 = *(const bf16x8*)(smem + j * 128 + ((hi * 16) ^ xm));
      const bf16x8 kb1 = *(const bf16x8*)(smem + j * 128 + ((64 + hi * 16) ^ xm));
      s[nf] = __builtin_amdgcn_mfma_f32_16x16x32_bf16(qa0, kb0, s[nf], 0, 0, 0);
      s[nf] = __builtin_amdgcn_mfma_f32_16x16x32_bf16(qa1, kb1, s[nf], 0, 0, 0);
    }

#pragma unroll
    for (int r = 0; r < 4; ++r) {
      float mx = -3.0e38f;
#pragma unroll
      for (int nf = 0; nf < 12; ++nf) mx = fmaxf(mx, s[nf][r]);
      if (l15 < 4) mx = fmaxf(mx, s[12][r]);
#pragma unroll
      for (int off = 1; off < 16; off <<= 1) mx = fmaxf(mx, __shfl_xor(mx, off));
      float sum = 0.f;
#pragma unroll
      for (int nf = 0; nf < 13; ++nf) {
        const bool valid = (nf < 12) || (l15 < 4);
        const float p = valid ? __expf((s[nf][r] - mx) * SCALE_) : 0.f;
        s[nf][r] = p; sum += p;
      }
#pragma unroll
      for (int off = 1; off < 16; off <<= 1) sum += __shfl_xor(sum, off);
      const float inv = 1.f / sum;
#pragma unroll
      for (int nf = 0; nf < 13; ++nf) s[nf][r] *= inv;
    }

#pragma unroll
    for (int r = 0; r < 4; ++r) {
      const int row = hi * 4 + r;
      const int rm = (row & 7) << 4;
      char* rp = sP + row * 512;
#pragma unroll
      for (int nf = 0; nf < 13; ++nf)
        *(__bf16*)(rp + (((nf * 16 + l15) * 2) ^ rm)) = (__bf16)s[nf][r];
      *(__bf16*)(rp + (((208 + l15) * 2) ^ rm)) = (__bf16)0.f;
    }

    f32x4 oa[7] = {};
#pragma unroll
    for (int kk = 0; kk < 7; ++kk) {
      const bf16x8 pa = *(const bf16x8*)(sP + l15 * 512 + ((kk * 64 + hi * 16) ^ xm));
#pragma unroll
      for (int nf = 0; nf < 7; ++nf) {
        const int d = nf * 16 + l15;
        const bf16x8 vbf = *(const bf16x8*)(sV + d * 512 + ((kk * 64 + hi * 16) ^ xm));
        oa[nf] = __builtin_amdgcn_mfma_f32_16x16x32_bf16(pa, vbf, oa[nf], 0, 0, 0);
      }
    }
#pragma unroll
    for (int nf = 0; nf < 7; ++nf)
#pragma unroll
      for (int r = 0; r < 4; ++r) {
        const int q = q0 + hi * 4 + r;
        if (q < 196) obase[(size_t)q * 896 + nf * 16 + l15] = (__bf16)oa[nf][r];
      }
  }
}

// ------------------------------- launch ------------------------------------
extern "C" void kernel_launch(void* const* d_in, const int* in_sizes, int n_in,
                              void* d_out, int out_size, void* d_ws, size_t ws_size,
                              hipStream_t stream) {
  (void)in_sizes; (void)n_in; (void)out_size; (void)ws_size;
  const float* x_in  = (const float*)d_in[0];
  const float* bn1_g = (const float*)d_in[1];
  const float* bn1_b = (const float*)d_in[2];
  const float* Wqk   = (const float*)d_in[3];
  const float* bqk   = (const float*)d_in[4];
  const float* Wv    = (const float*)d_in[5];
  const float* bv    = (const float*)d_in[6];
  const float* Wo    = (const float*)d_in[7];
  const float* bo    = (const float*)d_in[8];
  const float* bn2_g = (const float*)d_in[9];
  const float* bn2_b = (const float*)d_in[10];
  const float* W1    = (const float*)d_in[11];
  const float* b1    = (const float*)d_in[12];
  const float* bn3_g = (const float*)d_in[13];
  const float* bn3_b = (const float*)d_in[14];
  const float* W2    = (const float*)d_in[15];
  const float* b2    = (const float*)d_in[16];

  char* ws = (char*)d_ws;
  float*  xb   = (float*)(ws + 0);            // 12544x768 f32
  __bf16* wqkT = (__bf16*)(ws + 38535168);    // 6 x 1024 x 384
  __bf16* wvT  = (__bf16*)(ws + 43253760);    // 6 x 896 x 768
  __bf16* woT  = (__bf16*)(ws + 51511296);    // 6 x 768 x 896
  __bf16* w1T  = (__bf16*)(ws + 59768832);    // 6 x 768 x 768
  __bf16* w2T  = (__bf16*)(ws + 66846720);    // 6 x 768 x 768
  __bf16* hb   = (__bf16*)(ws + 73924608);    // 12544x768 bf16
  __bf16* qkb  = (__bf16*)(ws + 93192192);    // 12544x1024 bf16 (also f1 reuse)
  __bf16* vTb  = (__bf16*)(ws + 118882304);   // 896x12544 bf16 (V^T)
  __bf16* obuf = (__bf16*)(ws + 141361152);   // 12544x896 bf16
  float*  part = (float*)(ws + 163840000);    // 196x768x2 f32
  float*  sc   = (float*)(ws + 165044224);    // 2x768 f32
  float*  sAcc = (float*)(ws + 165051392);    // 768x2 f32 stats accumulator
  __bf16* f1b  = qkb;

  const dim3 tb(256);

  transpose_cvt<<<dim3(32, 12, 6), dim3(32, 8), 0, stream>>>(Wqk, wqkT, 384, 1024);
  transpose_cvt<<<dim3(28, 24, 6), dim3(32, 8), 0, stream>>>(Wv,  wvT,  768, 896);
  transpose_cvt<<<dim3(24, 28, 6), dim3(32, 8), 0, stream>>>(Wo,  woT,  896, 768);
  transpose_cvt<<<dim3(24, 24, 6), dim3(32, 8), 0, stream>>>(W1,  w1T,  768, 768);
  transpose_cvt<<<dim3(24, 24, 6), dim3(32, 8), 0, stream>>>(W2,  w2T,  768, 768);
  copy_f32<<<9408, tb, 0, stream>>>(x_in, xb);
  hipMemsetAsync(sAcc, 0, 768 * 2 * sizeof(float), stream);

  // layer-0 bn1 stats (standalone)
  bn_stats_part<<<dim3(3, 196), tb, 0, stream>>>(xb, part);
  bn_stats_fin<<<3, tb, 0, stream>>>(part, bn1_g, bn1_b, sc);

  for (int i = 0; i < 6; ++i) {
    const __bf16* wqkT_i = wqkT + (size_t)i * 1024 * 384;
    const __bf16* wvT_i  = wvT  + (size_t)i * 896 * 768;
    const __bf16* woT_i  = woT  + (size_t)i * 768 * 896;
    const __bf16* w1T_i  = w1T  + (size_t)i * 768 * 768;
    const __bf16* w2T_i  = w2T  + (size_t)i * 768 * 768;

    // --- attention block ---  (sc currently holds bn1 scale/shift)
    bn_apply_f32<<<9408, tb, 0, stream>>>(xb, sc, hb);
    gemm128<0, 0><<<dim3(98, 8), tb, 0, stream>>>(hb + 384, 768, wqkT_i, 384,
                                                  bqk + i * 1024, qkb, nullptr, 1024, nullptr);
    gemm128<2, 0><<<dim3(7, 98), tb, 0, stream>>>(wvT_i, 768, hb, 768,
                                                  bv + i * 896, vTb, nullptr, 12544, nullptr);
    attn_kernel<<<512, dim3(512), 0, stream>>>(qkb, vTb, obuf);
    gemm128<1, 1><<<dim3(98, 6), tb, 0, stream>>>(obuf, 896, woT_i, 896,
                                                  bo + i * 768, nullptr, xb, 768, sAcc);

    // --- feedforward block ---
    bn_fin2<<<3, tb, 0, stream>>>(sAcc, bn2_g + i * 768, bn2_b + i * 768, sc);
    bn_apply_f32<<<9408, tb, 0, stream>>>(xb, sc, hb);
    gemm128<0, 1><<<dim3(98, 6), tb, 0, stream>>>(hb, 768, w1T_i, 768,
                                                  b1 + i * 768, f1b, nullptr, 768, sAcc);
    bn_fin2<<<3, tb, 0, stream>>>(sAcc, bn3_g + i * 768, bn3_b + i * 768, sc);
    bn_gelu_apply<<<9408, tb, 0, stream>>>(f1b, sc, hb);
    if (i < 5) {
      gemm128<1, 1><<<dim3(98, 6), tb, 0, stream>>>(hb, 768, w2T_i, 768,
                                                    b2 + i * 768, nullptr, xb, 768, sAcc);
      bn_fin2<<<3, tb, 0, stream>>>(sAcc, bn1_g + (i + 1) * 768, bn1_b + (i + 1) * 768, sc);
    } else {
      gemm128<1, 0><<<dim3(98, 6), tb, 0, stream>>>(hb, 768, w2T_i, 768,
                                                    b2 + i * 768, nullptr, xb, 768, nullptr);
    }
  }
  copy_f32<<<9408, tb, 0, stream>>>(xb, (float*)d_out);
}

// Round 6
// 1408.410 us; speedup vs baseline: 1.3737x; 1.3319x over previous
//
#include <hip/hip_runtime.h>
#include <hip/hip_bf16.h>
#include <stdint.h>

// ---------------------------------------------------------------------------
// Transformer: 6 layers. fp32 residual stream + BN stats; bf16 MFMA GEMMs.
// R6: GEMM back to single-buffer 32KB LDS (occupancy is the latency-hider;
// R4/R5's dbuf halved blocks/CU and regressed). Keep T2 swizzle + fused
// stats (scol reuses dead sA space -> LDS = exactly 32KB -> 5 blocks/CU).
// NEW: XCD panel grouping — 1D grid remapped so all S blocks sharing an
// operand panel land on one XCD (bid&7), turning L3-latency re-reads into
// L2 hits.
// ---------------------------------------------------------------------------

typedef __bf16 bf16x8 __attribute__((ext_vector_type(8)));
typedef __bf16 bf16x4 __attribute__((ext_vector_type(4)));
typedef float  f32x4  __attribute__((ext_vector_type(4)));

#define DIM_  768
#define SCALE_ 0.125f

__device__ __forceinline__ void gload16(const void* g, void* l) {
  __builtin_amdgcn_global_load_lds(
      (__attribute__((address_space(1))) void*)(g),
      (__attribute__((address_space(3))) void*)(l), 16, 0, 0);
}

// ------------------------- weight transpose + cvt --------------------------
__global__ void transpose_cvt(const float* __restrict__ W, __bf16* __restrict__ WT,
                              int K, int N) {
  __shared__ float t[32][33];
  const size_t zoff = (size_t)blockIdx.z * K * N;
  W  += zoff; WT += zoff;
  const int bx = blockIdx.x * 32;
  const int by = blockIdx.y * 32;
  for (int j = threadIdx.y; j < 32; j += 8)
    t[j][threadIdx.x] = W[(size_t)(by + j) * N + bx + threadIdx.x];
  __syncthreads();
  for (int j = threadIdx.y; j < 32; j += 8)
    WT[(size_t)(bx + j) * K + by + threadIdx.x] = (__bf16)t[threadIdx.x][j];
}

// ------------------------------- copies ------------------------------------
__global__ void copy_f32(const float* __restrict__ src, float* __restrict__ dst) {
  const int i = blockIdx.x * 256 + threadIdx.x;
  *(f32x4*)(dst + (size_t)i * 4) = *(const f32x4*)(src + (size_t)i * 4);
}

// ------------------------------ BN stats (layer-0 bn1 only) ----------------
__global__ void bn_stats_part(const float* __restrict__ x, float* __restrict__ part) {
  const int col = blockIdx.x * 256 + threadIdx.x;
  const int r0  = blockIdx.y * 64;
  const float* p = x + (size_t)r0 * DIM_ + col;
  float s = 0.f, s2 = 0.f;
  for (int r = 0; r < 64; ++r) {
    float v = p[(size_t)r * DIM_];
    s += v; s2 += v * v;
  }
  float* q = part + ((size_t)blockIdx.y * DIM_ + col) * 2;
  q[0] = s; q[1] = s2;
}

__global__ void bn_stats_fin(const float* __restrict__ part, const float* __restrict__ g,
                             const float* __restrict__ b, float* __restrict__ sc) {
  const int col = blockIdx.x * 256 + threadIdx.x;
  float s = 0.f, s2 = 0.f;
  for (int p = 0; p < 196; ++p) {
    s  += part[((size_t)p * DIM_ + col) * 2];
    s2 += part[((size_t)p * DIM_ + col) * 2 + 1];
  }
  const float mean = s * (1.f / 12544.f);
  const float var  = s2 * (1.f / 12544.f) - mean * mean;
  const float rstd = rsqrtf(var + 1e-5f);
  const float scale = rstd * g[col];
  sc[col]        = scale;
  sc[DIM_ + col] = b[col] - mean * scale;
}

// finalize from atomically-accumulated [col][2] sums; self-zero for next use
__global__ void bn_fin2(float* __restrict__ acc, const float* __restrict__ g,
                        const float* __restrict__ b, float* __restrict__ sc) {
  const int col = blockIdx.x * 256 + threadIdx.x;
  const float s  = acc[col * 2];
  const float s2 = acc[col * 2 + 1];
  acc[col * 2] = 0.f; acc[col * 2 + 1] = 0.f;
  const float mean = s * (1.f / 12544.f);
  const float var  = s2 * (1.f / 12544.f) - mean * mean;
  const float rstd = rsqrtf(var + 1e-5f);
  const float scale = rstd * g[col];
  sc[col]        = scale;
  sc[DIM_ + col] = b[col] - mean * scale;
}

// ------------------------------ BN apply -----------------------------------
__global__ void bn_apply_f32(const float* __restrict__ x, const float* __restrict__ sc,
                             __bf16* __restrict__ h) {
  const int i = blockIdx.x * 256 + threadIdx.x;
  const int c4 = i % 192;
  f32x4 v  = *(const f32x4*)(x + (size_t)i * 4);
  f32x4 scl = *(const f32x4*)(sc + c4 * 4);
  f32x4 sh  = *(const f32x4*)(sc + DIM_ + c4 * 4);
  f32x4 y = v * scl + sh;
  bf16x4 o;
  o[0] = (__bf16)y[0]; o[1] = (__bf16)y[1]; o[2] = (__bf16)y[2]; o[3] = (__bf16)y[3];
  *(bf16x4*)(h + (size_t)i * 4) = o;
}

__global__ void bn_gelu_apply(const __bf16* __restrict__ f1, const float* __restrict__ sc,
                              __bf16* __restrict__ h) {
  const int i = blockIdx.x * 256 + threadIdx.x;
  const int c4 = i % 192;
  bf16x4 v4 = *(const bf16x4*)(f1 + (size_t)i * 4);
  f32x4 scl = *(const f32x4*)(sc + c4 * 4);
  f32x4 sh  = *(const f32x4*)(sc + DIM_ + c4 * 4);
  bf16x4 o;
#pragma unroll
  for (int j = 0; j < 4; ++j) {
    float y = (float)v4[j] * scl[j] + sh[j];
    float gl = 0.5f * y * (1.f + erff(y * 0.70710678118654752f));
    o[j] = (__bf16)gl;
  }
  *(bf16x4*)(h + (size_t)i * 4) = o;
}

// -------------------------------- GEMM -------------------------------------
// C[M x N] = A[M x K] @ BT[N x K]^T ; 128x128 tile, BK=64, 256 thr (4 waves).
// Single-buffer 2-phase (occupancy hides latency; 32KB LDS -> 4-5 blocks/CU).
// XCD panel grouping: 1D grid, c=bid&7 selects XCD-co-resident class;
// panel p = (r/S)*8+c (P panels), sharer s = r%S. PANEL_X: panel dim is M.
// LDS XOR-swizzled (chunk ^ (row&7)) via pre-swizzled global source.
// EPI 0: outB = bf16(acc + bias[col]); EPI 1: outF += acc + bias[col];
// EPI 2: outB = bf16(acc + bias[row]).
// STATS: per-column sum/sumsq of final values -> statsAcc (scol reuses sA).
template <int EPI, int STATS, int PANEL_X>
__global__ __launch_bounds__(256, 2) void gemm128(
    const __bf16* __restrict__ A, int lda,
    const __bf16* __restrict__ BT, int K,
    const float* __restrict__ bias,
    __bf16* __restrict__ outB, float* outF, int ldc,
    float* __restrict__ statsAcc, int P, int S) {
  __shared__ __bf16 sA[128 * 64];
  __shared__ __bf16 sB[128 * 64];
  const int bid = blockIdx.x;
  const int xcd = bid & 7, r0b = bid >> 3;
  const int pl = r0b / S, sh = r0b - pl * S;
  const int p = pl * 8 + xcd;
  if (p >= P) return;
  const int mx = PANEL_X ? p : sh;
  const int ny = PANEL_X ? sh : p;

  const int tid = threadIdx.x;
  const int lane = tid & 63, wv = tid >> 6;
  const int l15 = lane & 15, hi = lane >> 4;
  const int m0 = mx * 128, n0 = ny * 128;
  const __bf16* Ab = A + (size_t)m0 * lda;
  const __bf16* Bb = BT + (size_t)n0 * K;
  const int wr = (wv >> 1) * 64, wc = (wv & 1) * 64;

  f32x4 acc[4][4] = {};

#define STAGE(kt)                                                             \
  {                                                                           \
    const int k0_ = (kt) << 6;                                                \
    _Pragma("unroll")                                                         \
    for (int i_ = 0; i_ < 4; ++i_) {                                          \
      const int o_ = i_ * 4096 + tid * 16;                                    \
      const int row_ = o_ >> 7;                                               \
      const int j_ = (o_ >> 4) & 7;                                           \
      const int src_ = (j_ ^ (row_ & 7)) << 3;                                \
      gload16(Ab + (size_t)row_ * lda + k0_ + src_,                           \
              &sA[i_ * 2048 + wv * 512]);                                     \
      gload16(Bb + (size_t)row_ * K + k0_ + src_,                             \
              &sB[i_ * 2048 + wv * 512]);                                     \
    }                                                                         \
  }

  const int nkt = K >> 6;
  for (int kt = 0; kt < nkt; ++kt) {
    if (kt) __syncthreads();
    STAGE(kt);
    asm volatile("s_waitcnt vmcnt(0)" ::: "memory");
    __syncthreads();
    const char* cA = (const char*)sA;
    const char* cB = (const char*)sB;
#pragma unroll
    for (int ks = 0; ks < 2; ++ks) {
      bf16x8 af[4], bfr[4];
#pragma unroll
      for (int m = 0; m < 4; ++m) {
        const int row = wr + m * 16 + l15;
        af[m] = *(const bf16x8*)(cA + row * 128 +
                                 ((ks * 64 + hi * 16) ^ ((row & 7) << 4)));
      }
#pragma unroll
      for (int n = 0; n < 4; ++n) {
        const int row = wc + n * 16 + l15;
        bfr[n] = *(const bf16x8*)(cB + row * 128 +
                                  ((ks * 64 + hi * 16) ^ ((row & 7) << 4)));
      }
#pragma unroll
      for (int m = 0; m < 4; ++m)
#pragma unroll
        for (int n = 0; n < 4; ++n)
          acc[m][n] = __builtin_amdgcn_mfma_f32_16x16x32_bf16(af[m], bfr[n], acc[m][n], 0, 0, 0);
    }
  }
#undef STAGE

  float* scol = (float*)sA;   // sA dead after K-loop; reuse for stats reduce
  if (STATS) {
    __syncthreads();          // all waves done reading sA
    scol[tid] = 0.f;
    __syncthreads();
  }

  float cs[4], cs2[4];
  if (STATS)
#pragma unroll
    for (int n = 0; n < 4; ++n) { cs[n] = 0.f; cs2[n] = 0.f; }

#pragma unroll
  for (int m = 0; m < 4; ++m)
#pragma unroll
    for (int n = 0; n < 4; ++n) {
      const int cc = n0 + wc + n * 16 + l15;
      const float bc = (EPI == 2) ? 0.f : bias[cc];
#pragma unroll
      for (int r = 0; r < 4; ++r) {
        const int rr = m0 + wr + m * 16 + hi * 4 + r;
        const float val = acc[m][n][r] + ((EPI == 2) ? bias[rr] : bc);
        float fv;
        if (EPI == 1) {
          float* pp = outF + (size_t)rr * ldc + cc;
          fv = *pp + val;
          *pp = fv;
        } else {
          fv = val;
          outB[(size_t)rr * ldc + cc] = (__bf16)fv;
        }
        if (STATS) { cs[n] += fv; cs2[n] += fv * fv; }
      }
    }

  if (STATS) {
#pragma unroll
    for (int n = 0; n < 4; ++n) {
      float s = cs[n], s2 = cs2[n];
      s += __shfl_xor(s, 16); s2 += __shfl_xor(s2, 16);
      s += __shfl_xor(s, 32); s2 += __shfl_xor(s2, 32);
      if (lane < 16) {
        atomicAdd(&scol[(wc + n * 16 + l15) * 2], s);
        atomicAdd(&scol[(wc + n * 16 + l15) * 2 + 1], s2);
      }
    }
    __syncthreads();
    if (tid < 128) {
      atomicAdd(&statsAcc[(size_t)(n0 + tid) * 2], scol[tid * 2]);
      atomicAdd(&statsAcc[(size_t)(n0 + tid) * 2 + 1], scol[tid * 2 + 1]);
    }
  }
}

// ------------------------------ attention ----------------------------------
#define SV_OFF 26624
#define SP_OFF 83968
__global__ __launch_bounds__(512, 1) void attn_kernel(
    const __bf16* __restrict__ qk, const __bf16* __restrict__ vT,
    __bf16* __restrict__ og) {
  __shared__ __align__(16) char smem[149504];
  const int bh = blockIdx.x, bb = bh >> 3, hh = bh & 7;
  const int tid = threadIdx.x, lane = tid & 63, wv = tid >> 6;
  const int l15 = lane & 15, hi = lane >> 4;

  const __bf16* qbase = qk + (size_t)bb * (196 * 1024) + hh * 64;
  const __bf16* kbase = qbase + 512;
  const __bf16* vbase = vT + (size_t)(hh * 112) * 12544 + bb * 196;
  __bf16* obase = og + (size_t)bb * (196 * 896) + hh * 112;

  char* sV = smem + SV_OFF;
  char* sP = smem + SP_OFF + wv * 8192;

  for (int s = tid; s < 1664; s += 512) {
    const int n = s >> 3, j = s & 7;
    const int row = (n < 196) ? n : 195;
    const int k8 = j ^ (n & 7);
    gload16(kbase + (size_t)row * 1024 + k8 * 8, smem + ((s >> 6) << 10));
  }
  for (int c = tid; c < 112 * 49; c += 512) {
    const int d = c / 49, c8 = c - d * 49;
    const bf16x4 v4 = *(const bf16x4*)(vbase + (size_t)d * 12544 + c8 * 4);
    *(bf16x4*)(sV + d * 512 + ((c8 * 8) ^ ((d & 7) << 4))) = v4;
  }
  {
    bf16x4 z = {};
    for (int c = tid; c < 112 * 7; c += 512) {
      const int d = c / 7, c8 = 49 + (c - d * 7);
      *(bf16x4*)(sV + d * 512 + ((c8 * 8) ^ ((d & 7) << 4))) = z;
    }
  }
  asm volatile("s_waitcnt vmcnt(0)" ::: "memory");
  __syncthreads();

  const int xm = (l15 & 7) << 4;
  for (int qt = wv; qt < 13; qt += 8) {
    const int q0 = qt * 16;
    int qn = q0 + l15; if (qn > 195) qn = 195;
    const __bf16* qp = qbase + (size_t)qn * 1024 + hi * 8;
    const bf16x8 qa0 = *(const bf16x8*)(qp);
    const bf16x8 qa1 = *(const bf16x8*)(qp + 32);

    f32x4 s[13] = {};
#pragma unroll
    for (int nf = 0; nf < 13; ++nf) {
      const int j = nf * 16 + l15;
      const bf16x8 kb0 = *(const bf16x8*)(smem + j * 128 + ((hi * 16) ^ xm));
      const bf16x8 kb1 = *(const bf16x8*)(smem + j * 128 + ((64 + hi * 16) ^ xm));
      s[nf] = __builtin_amdgcn_mfma_f32_16x16x32_bf16(qa0, kb0, s[nf], 0, 0, 0);
      s[nf] = __builtin_amdgcn_mfma_f32_16x16x32_bf16(qa1, kb1, s[nf], 0, 0, 0);
    }

#pragma unroll
    for (int r = 0; r < 4; ++r) {
      float mx = -3.0e38f;
#pragma unroll
      for (int nf = 0; nf < 12; ++nf) mx = fmaxf(mx, s[nf][r]);
      if (l15 < 4) mx = fmaxf(mx, s[12][r]);
#pragma unroll
      for (int off = 1; off < 16; off <<= 1) mx = fmaxf(mx, __shfl_xor(mx, off));
      float sum = 0.f;
#pragma unroll
      for (int nf = 0; nf < 13; ++nf) {
        const bool valid = (nf < 12) || (l15 < 4);
        const float p = valid ? __expf((s[nf][r] - mx) * SCALE_) : 0.f;
        s[nf][r] = p; sum += p;
      }
#pragma unroll
      for (int off = 1; off < 16; off <<= 1) sum += __shfl_xor(sum, off);
      const float inv = 1.f / sum;
#pragma unroll
      for (int nf = 0; nf < 13; ++nf) s[nf][r] *= inv;
    }

#pragma unroll
    for (int r = 0; r < 4; ++r) {
      const int row = hi * 4 + r;
      const int rm = (row & 7) << 4;
      char* rp = sP + row * 512;
#pragma unroll
      for (int nf = 0; nf < 13; ++nf)
        *(__bf16*)(rp + (((nf * 16 + l15) * 2) ^ rm)) = (__bf16)s[nf][r];
      *(__bf16*)(rp + (((208 + l15) * 2) ^ rm)) = (__bf16)0.f;
    }

    f32x4 oa[7] = {};
#pragma unroll
    for (int kk = 0; kk < 7; ++kk) {
      const bf16x8 pa = *(const bf16x8*)(sP + l15 * 512 + ((kk * 64 + hi * 16) ^ xm));
#pragma unroll
      for (int nf = 0; nf < 7; ++nf) {
        const int d = nf * 16 + l15;
        const bf16x8 vbf = *(const bf16x8*)(sV + d * 512 + ((kk * 64 + hi * 16) ^ xm));
        oa[nf] = __builtin_amdgcn_mfma_f32_16x16x32_bf16(pa, vbf, oa[nf], 0, 0, 0);
      }
    }
#pragma unroll
    for (int nf = 0; nf < 7; ++nf)
#pragma unroll
      for (int r = 0; r < 4; ++r) {
        const int q = q0 + hi * 4 + r;
        if (q < 196) obase[(size_t)q * 896 + nf * 16 + l15] = (__bf16)oa[nf][r];
      }
  }
}

// ------------------------------- launch ------------------------------------
extern "C" void kernel_launch(void* const* d_in, const int* in_sizes, int n_in,
                              void* d_out, int out_size, void* d_ws, size_t ws_size,
                              hipStream_t stream) {
  (void)in_sizes; (void)n_in; (void)out_size; (void)ws_size;
  const float* x_in  = (const float*)d_in[0];
  const float* bn1_g = (const float*)d_in[1];
  const float* bn1_b = (const float*)d_in[2];
  const float* Wqk   = (const float*)d_in[3];
  const float* bqk   = (const float*)d_in[4];
  const float* Wv    = (const float*)d_in[5];
  const float* bv    = (const float*)d_in[6];
  const float* Wo    = (const float*)d_in[7];
  const float* bo    = (const float*)d_in[8];
  const float* bn2_g = (const float*)d_in[9];
  const float* bn2_b = (const float*)d_in[10];
  const float* W1    = (const float*)d_in[11];
  const float* b1    = (const float*)d_in[12];
  const float* bn3_g = (const float*)d_in[13];
  const float* bn3_b = (const float*)d_in[14];
  const float* W2    = (const float*)d_in[15];
  const float* b2    = (const float*)d_in[16];

  char* ws = (char*)d_ws;
  float*  xb   = (float*)(ws + 0);            // 12544x768 f32
  __bf16* wqkT = (__bf16*)(ws + 38535168);    // 6 x 1024 x 384
  __bf16* wvT  = (__bf16*)(ws + 43253760);    // 6 x 896 x 768
  __bf16* woT  = (__bf16*)(ws + 51511296);    // 6 x 768 x 896
  __bf16* w1T  = (__bf16*)(ws + 59768832);    // 6 x 768 x 768
  __bf16* w2T  = (__bf16*)(ws + 66846720);    // 6 x 768 x 768
  __bf16* hb   = (__bf16*)(ws + 73924608);    // 12544x768 bf16
  __bf16* qkb  = (__bf16*)(ws + 93192192);    // 12544x1024 bf16 (also f1 reuse)
  __bf16* vTb  = (__bf16*)(ws + 118882304);   // 896x12544 bf16 (V^T)
  __bf16* obuf = (__bf16*)(ws + 141361152);   // 12544x896 bf16
  float*  part = (float*)(ws + 163840000);    // 196x768x2 f32
  float*  sc   = (float*)(ws + 165044224);    // 2x768 f32
  float*  sAcc = (float*)(ws + 165051392);    // 768x2 f32 stats accumulator
  __bf16* f1b  = qkb;

  const dim3 tb(256);

  transpose_cvt<<<dim3(32, 12, 6), dim3(32, 8), 0, stream>>>(Wqk, wqkT, 384, 1024);
  transpose_cvt<<<dim3(28, 24, 6), dim3(32, 8), 0, stream>>>(Wv,  wvT,  768, 896);
  transpose_cvt<<<dim3(24, 28, 6), dim3(32, 8), 0, stream>>>(Wo,  woT,  896, 768);
  transpose_cvt<<<dim3(24, 24, 6), dim3(32, 8), 0, stream>>>(W1,  w1T,  768, 768);
  transpose_cvt<<<dim3(24, 24, 6), dim3(32, 8), 0, stream>>>(W2,  w2T,  768, 768);
  copy_f32<<<9408, tb, 0, stream>>>(x_in, xb);
  hipMemsetAsync(sAcc, 0, 768 * 2 * sizeof(float), stream);

  // layer-0 bn1 stats (standalone)
  bn_stats_part<<<dim3(3, 196), tb, 0, stream>>>(xb, part);
  bn_stats_fin<<<3, tb, 0, stream>>>(part, bn1_g, bn1_b, sc);

  // XCD-grouped 1D grids: 8 * ceil(98/8)=13 * S
  const int gQK = 8 * 13 * 8;   // P=98 panels (M), S=8 sharers (N tiles)
  const int gV  = 8 * 13 * 7;   // P=98 panels (N), S=7 sharers (M tiles)
  const int gO  = 8 * 13 * 6;   // P=98 panels (M), S=6 sharers (N tiles)

  for (int i = 0; i < 6; ++i) {
    const __bf16* wqkT_i = wqkT + (size_t)i * 1024 * 384;
    const __bf16* wvT_i  = wvT  + (size_t)i * 896 * 768;
    const __bf16* woT_i  = woT  + (size_t)i * 768 * 896;
    const __bf16* w1T_i  = w1T  + (size_t)i * 768 * 768;
    const __bf16* w2T_i  = w2T  + (size_t)i * 768 * 768;

    // --- attention block ---  (sc currently holds bn1 scale/shift)
    bn_apply_f32<<<9408, tb, 0, stream>>>(xb, sc, hb);
    gemm128<0, 0, 1><<<gQK, tb, 0, stream>>>(hb + 384, 768, wqkT_i, 384,
                                             bqk + i * 1024, qkb, nullptr, 1024,
                                             nullptr, 98, 8);
    gemm128<2, 0, 0><<<gV, tb, 0, stream>>>(wvT_i, 768, hb, 768,
                                            bv + i * 896, vTb, nullptr, 12544,
                                            nullptr, 98, 7);
    attn_kernel<<<512, dim3(512), 0, stream>>>(qkb, vTb, obuf);
    gemm128<1, 1, 1><<<gO, tb, 0, stream>>>(obuf, 896, woT_i, 896,
                                            bo + i * 768, nullptr, xb, 768,
                                            sAcc, 98, 6);

    // --- feedforward block ---
    bn_fin2<<<3, tb, 0, stream>>>(sAcc, bn2_g + i * 768, bn2_b + i * 768, sc);
    bn_apply_f32<<<9408, tb, 0, stream>>>(xb, sc, hb);
    gemm128<0, 1, 1><<<gO, tb, 0, stream>>>(hb, 768, w1T_i, 768,
                                            b1 + i * 768, f1b, nullptr, 768,
                                            sAcc, 98, 6);
    bn_fin2<<<3, tb, 0, stream>>>(sAcc, bn3_g + i * 768, bn3_b + i * 768, sc);
    bn_gelu_apply<<<9408, tb, 0, stream>>>(f1b, sc, hb);
    if (i < 5) {
      gemm128<1, 1, 1><<<gO, tb, 0, stream>>>(hb, 768, w2T_i, 768,
                                              b2 + i * 768, nullptr, xb, 768,
                                              sAcc, 98, 6);
      bn_fin2<<<3, tb, 0, stream>>>(sAcc, bn1_g + (i + 1) * 768, bn1_b + (i + 1) * 768, sc);
    } else {
      gemm128<1, 0, 1><<<gO, tb, 0, stream>>>(hb, 768, w2T_i, 768,
                                              b2 + i * 768, nullptr, xb, 768,
                                              nullptr, 98, 6);
    }
  }
  copy_f32<<<9408, tb, 0, stream>>>(xb, (float*)d_out);
}